// Round 4
// baseline (3001.294 us; speedup 1.0000x reference)
//
#include <hip/hip_runtime.h>
#include <stdint.h>
#include <type_traits>
#include <utility>

// Problem constants
#define L_   6
#define D_   512
#define MLP_ 2048
#define BB_  8
#define NN_  1024
#define ROWS_ 8192              // BB_*NN_
#define XSZ_  4194304           // ROWS_*D_   (output 0 size)
#define QKVSZ_ 12582912         // ROWS_*1536 (elements)
#define VTSZ_  4194304          // BB_*512*NN_ (elements)
#define FFSZ_  16777216         // ROWS_*2048 (elements)
#define ATTN_LAYER_SZ_ 8388608  // BB_*NN_*NN_ (per-layer attn slice)

typedef union { float4 v; float f[4]; } f4u;
typedef union { ushort4 v; ushort s[4]; } u4u;

typedef __attribute__((ext_vector_type(8))) short  s16x8;
typedef __attribute__((ext_vector_type(8))) __bf16 b16x8;
typedef __attribute__((ext_vector_type(4))) float  f32x4;

// Toolchain-portable fragment type for the gfx950 bf16 MFMA builtin.
template<class V, class = void> struct mfma_takes_short : std::false_type {};
template<class V> struct mfma_takes_short<V, std::void_t<decltype(
    __builtin_amdgcn_mfma_f32_16x16x32_bf16(std::declval<V>(), std::declval<V>(),
                                            std::declval<f32x4>(), 0, 0, 0))>>
    : std::true_type {};
using frag_t = std::conditional_t<mfma_takes_short<s16x8>::value, s16x8, b16x8>;

typedef union { frag_t f; ushort u[8]; } u8u;

__device__ __forceinline__ f32x4 mfma16(frag_t a, frag_t b, f32x4 c) {
  return __builtin_amdgcn_mfma_f32_16x16x32_bf16(a, b, c, 0, 0, 0);
}

// f32 -> bf16 (RNE) and back
__device__ __forceinline__ ushort f2bf(float x) {
  uint32_t u = __float_as_uint(x);
  u += 0x7fffu + ((u >> 16) & 1u);
  return (ushort)(u >> 16);
}
__device__ __forceinline__ float bf2f(ushort h) {
  return __uint_as_float(((uint32_t)h) << 16);
}

// async global->LDS, 16B per lane, wave-linear LDS destination
__device__ __forceinline__ void gll16(const void* g, void* l) {
  __builtin_amdgcn_global_load_lds((__attribute__((address_space(1))) void*)g,
                                   (__attribute__((address_space(3))) void*)l,
                                   16, 0, 0);
}

// ---------- LayerNorm: one wave per row (D=512 -> 8 elems/lane), emits bf16 hi/lo ----------
__global__ __launch_bounds__(256) void k_ln(const float* __restrict__ x,
                                            const float* __restrict__ g,
                                            const float* __restrict__ bia,
                                            ushort* __restrict__ hh,
                                            ushort* __restrict__ hl) {
    const int row  = blockIdx.x * 4 + (threadIdx.x >> 6);
    const int lane = threadIdx.x & 63;
    const float* xr = x + (size_t)row * D_;
    float v[8]; float s = 0.f, sq = 0.f;
    #pragma unroll
    for (int j = 0; j < 8; j++) { v[j] = xr[lane + j * 64]; s += v[j]; sq += v[j] * v[j]; }
    #pragma unroll
    for (int off = 32; off >= 1; off >>= 1) {
        s  += __shfl_xor(s, off, 64);
        sq += __shfl_xor(sq, off, 64);
    }
    const float mean = s * (1.f / D_);
    const float var  = sq * (1.f / D_) - mean * mean;
    const float rstd = rsqrtf(var + 1e-5f);
    ushort* hr = hh + (size_t)row * D_;
    ushort* lr = hl + (size_t)row * D_;
    #pragma unroll
    for (int j = 0; j < 8; j++) {
        int col = lane + j * 64;
        float y = (v[j] - mean) * rstd * g[col] + bia[col];
        ushort hi = f2bf(y);
        hr[col] = hi;
        lr[col] = f2bf(y - bf2f(hi));
    }
}

// ---------- one-time weight transpose + hi/lo split: W[l][K][N] -> T[l][N][K] ----------
__global__ __launch_bounds__(256) void k_wsplit(const float* __restrict__ W,
                                                ushort* __restrict__ Th,
                                                ushort* __restrict__ Tl,
                                                int K, int N) {
    __shared__ float t[64][65];
    const int n0 = blockIdx.x * 64, k0 = blockIdx.y * 64;
    const size_t lay = (size_t)blockIdx.z * K * N;
    const int tid = threadIdx.x;
    const int r = tid >> 4, c4 = (tid & 15) * 4;
    #pragma unroll
    for (int p = 0; p < 4; p++) {
        const float4 v = *(const float4*)(W + lay + (size_t)(k0 + r + p * 16) * N + n0 + c4);
        t[r + p * 16][c4 + 0] = v.x; t[r + p * 16][c4 + 1] = v.y;
        t[r + p * 16][c4 + 2] = v.z; t[r + p * 16][c4 + 3] = v.w;
    }
    __syncthreads();
    #pragma unroll
    for (int p = 0; p < 4; p++) {
        const int n = r + p * 16;
        u4u hv, lv;
        #pragma unroll
        for (int j = 0; j < 4; j++) {
            const float x = t[c4 + j][n];
            const ushort hi = f2bf(x);
            hv.s[j] = hi;
            lv.s[j] = f2bf(x - bf2f(hi));
        }
        *(ushort4*)(Th + lay + (size_t)(n0 + n) * K + k0 + c4) = hv.v;
        *(ushort4*)(Tl + lay + (size_t)(n0 + n) * K + k0 + c4) = lv.v;
    }
}

// ---------- MFMA GEMM: C[M,N] = A[M,K] @ B^T[N,K]^T, bf16 inputs, f32 accumulate ----------
// DUAL: A/B have hi+lo planes, 3 MFMA passes. 128x128 tile, BK=32, 4 waves, 4x4 frags.
// EMIT: 0 = f32 only; 1 = f32 + bf16-hi; 2 = bf16 hi+lo;
//       3 = qkv mode: bf16-hi for q/k cols, packed per-head K (Ck), transposed V (Cv).
template<bool DUAL, int EMIT, bool BIAS, bool RES, bool GELU>
__global__ __launch_bounds__(256, 2) void k_mm(
        const ushort* __restrict__ Ah, const ushort* __restrict__ Al, int lda, long sA,
        const ushort* __restrict__ Bh, const ushort* __restrict__ Bl, int ldb, long sB,
        const float* __restrict__ bias, const float* __restrict__ res,
        float* __restrict__ Cf, ushort* __restrict__ Ch, ushort* __restrict__ Cl,
        ushort* __restrict__ Ck, ushort* __restrict__ Cv,
        int ldc, long sC, int K, float scale)
{
    constexpr int HL = DUAL ? 2 : 1;
    constexpr int NQ = DUAL ? 8 : 4;     // global_load_lds chunks per wave per K-step
    __shared__ __align__(16) ushort As[HL][4][128][8];
    __shared__ __align__(16) ushort Bs[HL][4][128][8];
    const int tid = threadIdx.x, lane = tid & 63, wid = tid >> 6;
    const int m0 = blockIdx.y * 128, n0 = blockIdx.x * 128;
    const int z = blockIdx.z;
    Ah += (size_t)z * sA;  Bh += (size_t)z * sB;
    if constexpr (DUAL) { Al += (size_t)z * sA; Bl += (size_t)z * sB; }

    const ushort* gsrc[NQ];
    ushort*       ldst[NQ];
    #pragma unroll
    for (int q = 0; q < NQ; ++q) {
        const int cid = q * 4 + wid;
        const int p   = cid >> 3;
        const int cp  = cid & 7;
        const int s   = cp * 64 + lane;
        const int g   = s >> 7;
        const int pr  = s & 127;
        const int row = pr ^ g;
        const bool isA = p < HL;
        const ushort* base;
        ushort* plbase;
        if constexpr (DUAL) {
            base   = (p == 0) ? Ah : (p == 1) ? Al : (p == 2) ? Bh : Bl;
            plbase = (p < 2) ? &As[p][0][0][0] : &Bs[p - 2][0][0][0];
        } else {
            base   = (p == 0) ? Ah : Bh;
            plbase = (p == 0) ? &As[0][0][0][0] : &Bs[0][0][0][0];
        }
        const int mn = isA ? m0 : n0;
        const int ld = isA ? lda : ldb;
        gsrc[q] = base + (size_t)(mn + row) * ld + g * 8;
        ldst[q] = plbase + cp * 512;
    }

    f32x4 acc[4][4] = {};
    const int g4 = lane >> 4, r15 = lane & 15;
    const int wm = wid >> 1, wn = wid & 1;

    #pragma unroll
    for (int q = 0; q < NQ; ++q) gll16(gsrc[q], ldst[q]);

    for (int k0 = 0; k0 < K; k0 += 32) {
        __syncthreads();
        frag_t a_h[4], a_l[4], b_h[4], b_l[4];
        #pragma unroll
        for (int i = 0; i < 4; ++i) {
            const int pr = (wm * 64 + i * 16 + r15) ^ g4;
            a_h[i] = *(const frag_t*)&As[0][g4][pr][0];
            if constexpr (DUAL) a_l[i] = *(const frag_t*)&As[1][g4][pr][0];
        }
        #pragma unroll
        for (int j = 0; j < 4; ++j) {
            const int pr = (wn * 64 + j * 16 + r15) ^ g4;
            b_h[j] = *(const frag_t*)&Bs[0][g4][pr][0];
            if constexpr (DUAL) b_l[j] = *(const frag_t*)&Bs[1][g4][pr][0];
        }
        __syncthreads();
        if (k0 + 32 < K) {
            #pragma unroll
            for (int q = 0; q < NQ; ++q) gll16(gsrc[q] + (k0 + 32), ldst[q]);
        }
        #pragma unroll
        for (int i = 0; i < 4; ++i)
            #pragma unroll
            for (int j = 0; j < 4; ++j) {
                acc[i][j] = mfma16(a_h[i], b_h[j], acc[i][j]);
                if constexpr (DUAL) {
                    acc[i][j] = mfma16(a_h[i], b_l[j], acc[i][j]);
                    acc[i][j] = mfma16(a_l[i], b_h[j], acc[i][j]);
                }
            }
    }

    if constexpr (EMIT == 3) {
        // qkv mode: q/k cols -> bf16-hi row-major (scores + flash-Q);
        // k cols also -> packed per-head kh[b*8+h][n][64]; v cols -> vt[b*512+c][n] only.
        #pragma unroll
        for (int i = 0; i < 4; ++i) {
            const int row0 = m0 + wm * 64 + i * 16 + g4 * 4;   // 4 consecutive rows
            const int bq = row0 >> 10, n = row0 & 1023;
            #pragma unroll
            for (int j = 0; j < 4; ++j) {
                const int col = n0 + wn * 64 + j * 16 + r15;
                u4u pk;
                #pragma unroll
                for (int r = 0; r < 4; ++r) pk.s[r] = f2bf(acc[i][j][r]);
                if (col < 1024) {
                    #pragma unroll
                    for (int r = 0; r < 4; ++r)
                        Ch[(size_t)(row0 + r) * ldc + col] = pk.s[r];
                }
                if (col >= 1024) {
                    const int c = col - 1024;          // h*64 + d
                    *(ushort4*)(Cv + (((size_t)(bq * 512 + c)) << 10) + n) = pk.v;
                } else if (col >= 512) {
                    const int c = col - 512;           // h*64 + d
                    const size_t base = ((size_t)(bq * 8 + (c >> 6)) * 1024 + n) * 64 + (c & 63);
                    #pragma unroll
                    for (int r = 0; r < 4; ++r) Ck[base + (size_t)r * 64] = pk.s[r];
                }
            }
        }
    } else {
        if constexpr (EMIT == 0 || EMIT == 1) Cf += (size_t)z * sC;
        #pragma unroll
        for (int i = 0; i < 4; ++i)
            #pragma unroll
            for (int r = 0; r < 4; ++r) {
                const int row = m0 + wm * 64 + i * 16 + g4 * 4 + r;
                #pragma unroll
                for (int j = 0; j < 4; ++j) {
                    const int col = n0 + wn * 64 + j * 16 + r15;
                    float vv = acc[i][j][r] * scale;
                    if constexpr (BIAS) vv += bias[col];
                    if constexpr (RES)  vv += res[(size_t)row * ldc + col];
                    if constexpr (GELU) vv = 0.5f * vv * (1.f + erff(vv * 0.70710678118654752f));
                    const size_t o = (size_t)row * ldc + col;
                    if constexpr (EMIT == 0 || EMIT == 1) Cf[o] = vv;
                    if constexpr (EMIT == 1) Ch[o] = f2bf(vv);
                    if constexpr (EMIT == 2) {
                        const ushort hi = f2bf(vv);
                        Ch[o] = hi;
                        Cl[o] = f2bf(vv - bf2f(hi));
                    }
                }
            }
    }
}

// ---------- row softmax (1024 cols) in place, f32 ----------
__global__ __launch_bounds__(256) void k_softmax(float* __restrict__ sf) {
    const int row = blockIdx.x;
    const int tid = threadIdx.x;
    float4* rp = (float4*)(sf + ((size_t)row << 10));
    const float4 v = rp[tid];
    float mx = fmaxf(fmaxf(v.x, v.y), fmaxf(v.z, v.w));
    #pragma unroll
    for (int off = 32; off >= 1; off >>= 1) mx = fmaxf(mx, __shfl_xor(mx, off, 64));
    __shared__ float rmax[4], rsum[4];
    if ((tid & 63) == 0) rmax[tid >> 6] = mx;
    __syncthreads();
    mx = fmaxf(fmaxf(rmax[0], rmax[1]), fmaxf(rmax[2], rmax[3]));
    float e0 = expf(v.x - mx), e1 = expf(v.y - mx), e2 = expf(v.z - mx), e3 = expf(v.w - mx);
    float s = e0 + e1 + e2 + e3;
    #pragma unroll
    for (int off = 32; off >= 1; off >>= 1) s += __shfl_xor(s, off, 64);
    if ((tid & 63) == 0) rsum[tid >> 6] = s;
    __syncthreads();
    s = rsum[0] + rsum[1] + rsum[2] + rsum[3];
    const float inv = 1.f / s;
    rp[tid] = make_float4(e0 * inv, e1 * inv, e2 * inv, e3 * inv);
}

// ---------- per-head flash attention, MFMA bf16, XCD-pinned K/V reuse ----------
// 1-D grid of 1024 blocks; swizzle so XCD x (= bid%8) gets all 16 q-tiles of pairs
// pid in {x, x+8, ..., x+56}: 8 pairs x 256KB K/V = 2MB, fits per-XCD L2.
// Q from qkv_h, K from packed kh (128B rows), V from vt (transposed). P transposed
// through a per-wave LDS bounce. O accumulates f32; emits bf16 hi/lo.
__global__ __launch_bounds__(256) void k_flash(const ushort* __restrict__ qkv,
                                               const ushort* __restrict__ kh,
                                               const ushort* __restrict__ vt,
                                               ushort* __restrict__ oh,
                                               ushort* __restrict__ ol) {
    const int bid = blockIdx.x;
    const int xcd = bid & 7, jj = bid >> 3;
    const int qt  = jj & 15;
    const int pid = xcd + 8 * (jj >> 4);       // 0..63
    const int b = pid >> 3, h = pid & 7;
    const int tid = threadIdx.x, lane = tid & 63, wid = tid >> 6;
    const int g4 = lane >> 4, r15 = lane & 15;
    __shared__ ushort Pt[4][64][20];           // [wave][k][q], stride 20 to spread banks
    ushort (*pw)[20] = Pt[wid];

    const int q0 = qt * 64 + wid * 16;
    frag_t qa[2];
    {
        const ushort* qp = qkv + (size_t)(b * NN_ + q0 + r15) * 1536 + h * 64 + g4 * 8;
        qa[0] = *(const frag_t*)qp;
        qa[1] = *(const frag_t*)(qp + 32);
    }
    const ushort* kbase = kh + ((size_t)(b * 8 + h) << 16) + g4 * 8;   // [n][64]
    const ushort* vbase = vt + ((size_t)(b * 8 + h) * 64) * 1024 + g4 * 8;

    float m[4], l[4];
    f32x4 O[4];
    #pragma unroll
    for (int r = 0; r < 4; r++) { m[r] = -INFINITY; l[r] = 0.f; }
    #pragma unroll
    for (int j = 0; j < 4; j++) O[j] = (f32x4){0.f, 0.f, 0.f, 0.f};

    for (int kt = 0; kt < 16; kt++) {
        // K fragments: S col j -> k-row kt*64 + j*16 + r15 (128B row stride)
        frag_t kf[4][2];
        #pragma unroll
        for (int j = 0; j < 4; j++) {
            const ushort* kp = kbase + (size_t)(kt * 64 + j * 16 + r15) * 64;
            kf[j][0] = *(const frag_t*)kp;
            kf[j][1] = *(const frag_t*)(kp + 32);
        }
        // V fragments: O col j -> d = 16j + r15, k-run kt*64 + g4*8 (+32)
        frag_t vf[4][2];
        #pragma unroll
        for (int j = 0; j < 4; j++) {
            const ushort* vp = vbase + (size_t)(j * 16 + r15) * 1024 + kt * 64;
            vf[j][0] = *(const frag_t*)vp;
            vf[j][1] = *(const frag_t*)(vp + 32);
        }
        // S = Q @ K^T  (C-layout: row q = 4*g4+reg, col k = 16j + r15)
        f32x4 S[4];
        #pragma unroll
        for (int j = 0; j < 4; j++) {
            f32x4 s = {0.f, 0.f, 0.f, 0.f};
            s = mfma16(qa[0], kf[j][0], s);
            s = mfma16(qa[1], kf[j][1], s);
            S[j] = s * 0.125f;
        }
        // online softmax per row (reduction across the 16 lanes of this g4 group)
        float alpha[4];
        #pragma unroll
        for (int r = 0; r < 4; r++) {
            float mx = fmaxf(fmaxf(S[0][r], S[1][r]), fmaxf(S[2][r], S[3][r]));
            #pragma unroll
            for (int off = 1; off < 16; off <<= 1) mx = fmaxf(mx, __shfl_xor(mx, off, 16));
            const float mn = fmaxf(m[r], mx);
            alpha[r] = __expf(m[r] - mn);
            m[r] = mn;
        }
        #pragma unroll
        for (int j = 0; j < 4; j++)
            #pragma unroll
            for (int r = 0; r < 4; r++) S[j][r] = __expf(S[j][r] - m[r]);
        #pragma unroll
        for (int r = 0; r < 4; r++) {
            float s = S[0][r] + S[1][r] + S[2][r] + S[3][r];
            #pragma unroll
            for (int off = 1; off < 16; off <<= 1) s += __shfl_xor(s, off, 16);
            l[r] = l[r] * alpha[r] + s;
        }
        #pragma unroll
        for (int j = 0; j < 4; j++) {
            f32x4 o = O[j];
            #pragma unroll
            for (int r = 0; r < 4; r++) o[r] *= alpha[r];
            O[j] = o;
        }
        // P -> LDS (transpose bounce): Pt[k = 16j + r15][q = 4*g4 + reg]
        asm volatile("s_waitcnt lgkmcnt(0)" ::: "memory");
        #pragma unroll
        for (int j = 0; j < 4; j++) {
            u4u pk;
            #pragma unroll
            for (int r = 0; r < 4; r++) pk.s[r] = f2bf(S[j][r]);
            *(ushort4*)&pw[j * 16 + r15][g4 * 4] = pk.v;
        }
        asm volatile("s_waitcnt lgkmcnt(0)" ::: "memory");
        // P as A-operand: lane holds P[q = r15][k = g4*8 .. +7] (+32)
        frag_t pa[2];
        {
            u8u t0, t1;
            #pragma unroll
            for (int e = 0; e < 8; e++) {
                t0.u[e] = pw[g4 * 8 + e][r15];
                t1.u[e] = pw[32 + g4 * 8 + e][r15];
            }
            pa[0] = t0.f; pa[1] = t1.f;
        }
        #pragma unroll
        for (int j = 0; j < 4; j++) {
            O[j] = mfma16(pa[0], vf[j][0], O[j]);
            O[j] = mfma16(pa[1], vf[j][1], O[j]);
        }
    }
    // epilogue: normalize, emit bf16 hi/lo
    #pragma unroll
    for (int r = 0; r < 4; r++) {
        const float inv = 1.f / l[r];
        const size_t rbase = (size_t)(b * NN_ + q0 + 4 * g4 + r) * 512 + h * 64;
        #pragma unroll
        for (int j = 0; j < 4; j++) {
            const float y = O[j][r] * inv;
            const ushort hi = f2bf(y);
            oh[rbase + j * 16 + r15] = hi;
            ol[rbase + j * 16 + r15] = f2bf(y - bf2f(hi));
        }
    }
}

extern "C" void kernel_launch(void* const* d_in, const int* in_sizes, int n_in,
                              void* d_out, int out_size, void* d_ws, size_t ws_size,
                              hipStream_t stream) {
    (void)in_sizes; (void)n_in; (void)out_size; (void)ws_size;
    const float* x_in  = (const float*)d_in[0];
    const float* ln1_g = (const float*)d_in[1];
    const float* ln1_b = (const float*)d_in[2];
    const float* w_qkv = (const float*)d_in[3];
    const float* w_o   = (const float*)d_in[4];
    const float* b_o   = (const float*)d_in[5];
    const float* ln2_g = (const float*)d_in[6];
    const float* ln2_b = (const float*)d_in[7];
    const float* w1    = (const float*)d_in[8];
    const float* b1    = (const float*)d_in[9];
    const float* w2    = (const float*)d_in[10];
    const float* b2    = (const float*)d_in[11];
    float* out_x    = (float*)d_out;            // [8192, 512]
    float* out_attn = (float*)d_out + XSZ_;     // [6, 8, 1024, 1024]

    // workspace: xf | h hi/lo | qkv_h | vt | kh | ff_l | W^T  (ff_h aliases qkv_h+vt exactly)
    float*  xf    = (float*)d_ws;               // 16.8 MB
    ushort* h_hi  = (ushort*)(xf + XSZ_);       //  8.4 MB
    ushort* h_lo  = h_hi + XSZ_;                //  8.4 MB
    ushort* qkv_h = h_lo + XSZ_;                // 25.2 MB
    ushort* vtb   = qkv_h + QKVSZ_;             //  8.4 MB
    ushort* khb   = vtb + VTSZ_;                //  8.4 MB
    ushort* ff_h  = qkv_h;                      // aliases qkv_h+vt exactly (FFSZ_ elements)
    ushort* ff_l  = khb + VTSZ_;                // 33.6 MB
    ushort* wq_h  = ff_l + FFSZ_;               // W^T planes, 75.5 MB total
    ushort* wq_l  = wq_h + (size_t)6 * 786432;
    ushort* wo_h  = wq_l + (size_t)6 * 786432;
    ushort* wo_l  = wo_h + (size_t)6 * 262144;
    ushort* w1_h  = wo_l + (size_t)6 * 262144;
    ushort* w1_l  = w1_h + (size_t)6 * 1048576;
    ushort* w2_h  = w1_l + (size_t)6 * 1048576;
    ushort* w2_l  = w2_h + (size_t)6 * 1048576;

    k_wsplit<<<dim3(24, 8, 6), 256, 0, stream>>>(w_qkv, wq_h, wq_l, 512, 1536);
    k_wsplit<<<dim3( 8, 8, 6), 256, 0, stream>>>(w_o,   wo_h, wo_l, 512, 512);
    k_wsplit<<<dim3(32, 8, 6), 256, 0, stream>>>(w1,    w1_h, w1_l, 512, 2048);
    k_wsplit<<<dim3( 8,32, 6), 256, 0, stream>>>(w2,    w2_h, w2_l, 2048, 512);
    hipMemcpyAsync(xf, x_in, (size_t)XSZ_ * sizeof(float), hipMemcpyDeviceToDevice, stream);

    for (int l = 0; l < L_; l++) {
        float* attn_l = out_attn + (size_t)l * ATTN_LAYER_SZ_;
        // PreNorm attention
        k_ln<<<2048, 256, 0, stream>>>(xf, ln1_g + l * 512, ln1_b + l * 512, h_hi, h_lo);
        // qkv = h @ w_qkv : dual 3-pass; emits bf16-hi (q,k) + packed K + transposed V
        k_mm<true, 3, false, false, false><<<dim3(12, 64), 256, 0, stream>>>(
            h_hi, h_lo, 512, 0, wq_h + (size_t)l * 786432, wq_l + (size_t)l * 786432, 512, 0,
            nullptr, nullptr, nullptr, qkv_h, nullptr, khb, vtb, 1536, 0, 512, 1.f);
        // full-dim scores = (q @ k^T) * 512^-0.5 : plain bf16
        k_mm<false, 0, false, false, false><<<dim3(8, 8, 8), 256, 0, stream>>>(
            qkv_h, nullptr, 1536, (long)NN_ * 1536, qkv_h + 512, nullptr, 1536, (long)NN_ * 1536,
            nullptr, nullptr, attn_l, nullptr, nullptr, nullptr, nullptr, 1024, (long)NN_ * NN_,
            512, 0.044194173824159216f);
        k_softmax<<<8192, 256, 0, stream>>>(attn_l);
        // per-head flash attention (MFMA bf16, XCD-pinned) -> o in h hi/lo
        k_flash<<<1024, 256, 0, stream>>>(qkv_h, khb, vtb, h_hi, h_lo);
        // x += o @ w_o + b_o
        k_mm<true, 0, true, true, false><<<dim3(4, 64), 256, 0, stream>>>(
            h_hi, h_lo, 512, 0, wo_h + (size_t)l * 262144, wo_l + (size_t)l * 262144, 512, 0,
            b_o + l * 512, xf, xf, nullptr, nullptr, nullptr, nullptr, 512, 0, 512, 1.f);
        // PreNorm FFN
        k_ln<<<2048, 256, 0, stream>>>(xf, ln2_g + l * 512, ln2_b + l * 512, h_hi, h_lo);
        k_mm<true, 2, true, false, true><<<dim3(16, 64), 256, 0, stream>>>(
            h_hi, h_lo, 512, 0, w1_h + (size_t)l * 1048576, w1_l + (size_t)l * 1048576, 512, 0,
            b1 + l * 2048, nullptr, nullptr, ff_h, ff_l, nullptr, nullptr, 2048, 0, 512, 1.f);
        k_mm<true, 0, true, true, false><<<dim3(4, 64), 256, 0, stream>>>(
            ff_h, ff_l, 2048, 0, w2_h + (size_t)l * 1048576, w2_l + (size_t)l * 1048576, 2048, 0,
            b2 + l * 512, xf, (l == L_ - 1) ? out_x : xf, nullptr, nullptr, nullptr, nullptr,
            512, 0, 2048, 1.f);
    }
}

// Round 6
// 2725.947 us; speedup vs baseline: 1.1010x; 1.1010x over previous
//
#include <hip/hip_runtime.h>
#include <stdint.h>
#include <type_traits>
#include <utility>

// Problem constants
#define L_   6
#define D_   512
#define MLP_ 2048
#define BB_  8
#define NN_  1024
#define ROWS_ 8192              // BB_*NN_
#define XSZ_  4194304           // ROWS_*D_   (output 0 size)
#define QKVSZ_ 12582912         // ROWS_*1536 (elements)
#define VTSZ_  4194304          // BB_*512*NN_ (elements)
#define FFSZ_  16777216         // ROWS_*2048 (elements)
#define ATTN_LAYER_SZ_ 8388608  // BB_*NN_*NN_ (per-layer attn slice)

typedef union { float4 v; float f[4]; } f4u;
typedef union { ushort4 v; ushort s[4]; } u4u;

typedef __attribute__((ext_vector_type(8))) short  s16x8;
typedef __attribute__((ext_vector_type(8))) __bf16 b16x8;
typedef __attribute__((ext_vector_type(4))) float  f32x4;

// Toolchain-portable fragment type for the gfx950 bf16 MFMA builtin.
template<class V, class = void> struct mfma_takes_short : std::false_type {};
template<class V> struct mfma_takes_short<V, std::void_t<decltype(
    __builtin_amdgcn_mfma_f32_16x16x32_bf16(std::declval<V>(), std::declval<V>(),
                                            std::declval<f32x4>(), 0, 0, 0))>>
    : std::true_type {};
using frag_t = std::conditional_t<mfma_takes_short<s16x8>::value, s16x8, b16x8>;

typedef union { frag_t f; ushort u[8]; } u8u;

__device__ __forceinline__ f32x4 mfma16(frag_t a, frag_t b, f32x4 c) {
  return __builtin_amdgcn_mfma_f32_16x16x32_bf16(a, b, c, 0, 0, 0);
}

// f32 -> bf16 (RNE) and back
__device__ __forceinline__ ushort f2bf(float x) {
  uint32_t u = __float_as_uint(x);
  u += 0x7fffu + ((u >> 16) & 1u);
  return (ushort)(u >> 16);
}
__device__ __forceinline__ float bf2f(ushort h) {
  return __uint_as_float(((uint32_t)h) << 16);
}

// async global->LDS, 16B per lane, wave-linear LDS destination
__device__ __forceinline__ void gll16(const void* g, void* l) {
  __builtin_amdgcn_global_load_lds((__attribute__((address_space(1))) void*)g,
                                   (__attribute__((address_space(3))) void*)l,
                                   16, 0, 0);
}

// ---------- LayerNorm: one wave per row (D=512 -> 8 elems/lane), emits bf16 hi/lo ----------
__global__ __launch_bounds__(256) void k_ln(const float* __restrict__ x,
                                            const float* __restrict__ g,
                                            const float* __restrict__ bia,
                                            ushort* __restrict__ hh,
                                            ushort* __restrict__ hl) {
    const int row  = blockIdx.x * 4 + (threadIdx.x >> 6);
    const int lane = threadIdx.x & 63;
    const float* xr = x + (size_t)row * D_;
    float v[8]; float s = 0.f, sq = 0.f;
    #pragma unroll
    for (int j = 0; j < 8; j++) { v[j] = xr[lane + j * 64]; s += v[j]; sq += v[j] * v[j]; }
    #pragma unroll
    for (int off = 32; off >= 1; off >>= 1) {
        s  += __shfl_xor(s, off, 64);
        sq += __shfl_xor(sq, off, 64);
    }
    const float mean = s * (1.f / D_);
    const float var  = sq * (1.f / D_) - mean * mean;
    const float rstd = rsqrtf(var + 1e-5f);
    ushort* hr = hh + (size_t)row * D_;
    ushort* lr = hl + (size_t)row * D_;
    #pragma unroll
    for (int j = 0; j < 8; j++) {
        int col = lane + j * 64;
        float y = (v[j] - mean) * rstd * g[col] + bia[col];
        ushort hi = f2bf(y);
        hr[col] = hi;
        lr[col] = f2bf(y - bf2f(hi));
    }
}

// ---------- one-time weight transpose + hi/lo split: W[l][K][N] -> T[l][N][K] ----------
__global__ __launch_bounds__(256) void k_wsplit(const float* __restrict__ W,
                                                ushort* __restrict__ Th,
                                                ushort* __restrict__ Tl,
                                                int K, int N) {
    __shared__ float t[64][65];
    const int n0 = blockIdx.x * 64, k0 = blockIdx.y * 64;
    const size_t lay = (size_t)blockIdx.z * K * N;
    const int tid = threadIdx.x;
    const int r = tid >> 4, c4 = (tid & 15) * 4;
    #pragma unroll
    for (int p = 0; p < 4; p++) {
        const float4 v = *(const float4*)(W + lay + (size_t)(k0 + r + p * 16) * N + n0 + c4);
        t[r + p * 16][c4 + 0] = v.x; t[r + p * 16][c4 + 1] = v.y;
        t[r + p * 16][c4 + 2] = v.z; t[r + p * 16][c4 + 3] = v.w;
    }
    __syncthreads();
    #pragma unroll
    for (int p = 0; p < 4; p++) {
        const int n = r + p * 16;
        u4u hv, lv;
        #pragma unroll
        for (int j = 0; j < 4; j++) {
            const float x = t[c4 + j][n];
            const ushort hi = f2bf(x);
            hv.s[j] = hi;
            lv.s[j] = f2bf(x - bf2f(hi));
        }
        *(ushort4*)(Th + lay + (size_t)(n0 + n) * K + k0 + c4) = hv.v;
        *(ushort4*)(Tl + lay + (size_t)(n0 + n) * K + k0 + c4) = lv.v;
    }
}

// ---------- MFMA GEMM: C[M,N] = A[M,K] @ B^T[N,K]^T, bf16 inputs, f32 accumulate ----------
// DUAL: A/B have hi+lo planes, 3 MFMA passes. 128x128 tile, BK=32, 4 waves, 4x4 frags.
// EMIT: 0 = f32 only; 2 = bf16 hi+lo;
//       3 = qkv mode: bf16-hi for q cols, packed per-head K (Ck), transposed V (Cv).
template<bool DUAL, int EMIT, bool BIAS, bool RES, bool GELU>
__global__ __launch_bounds__(256, 2) void k_mm(
        const ushort* __restrict__ Ah, const ushort* __restrict__ Al, int lda, long sA,
        const ushort* __restrict__ Bh, const ushort* __restrict__ Bl, int ldb, long sB,
        const float* __restrict__ bias, const float* __restrict__ res,
        float* __restrict__ Cf, ushort* __restrict__ Ch, ushort* __restrict__ Cl,
        ushort* __restrict__ Ck, ushort* __restrict__ Cv,
        int ldc, long sC, int K, float scale)
{
    constexpr int HL = DUAL ? 2 : 1;
    constexpr int NQ = DUAL ? 8 : 4;     // global_load_lds chunks per wave per K-step
    __shared__ __align__(16) ushort As[HL][4][128][8];
    __shared__ __align__(16) ushort Bs[HL][4][128][8];
    const int tid = threadIdx.x, lane = tid & 63, wid = tid >> 6;
    const int m0 = blockIdx.y * 128, n0 = blockIdx.x * 128;
    const int z = blockIdx.z;
    Ah += (size_t)z * sA;  Bh += (size_t)z * sB;
    if constexpr (DUAL) { Al += (size_t)z * sA; Bl += (size_t)z * sB; }

    const ushort* gsrc[NQ];
    ushort*       ldst[NQ];
    #pragma unroll
    for (int q = 0; q < NQ; ++q) {
        const int cid = q * 4 + wid;
        const int p   = cid >> 3;
        const int cp  = cid & 7;
        const int s   = cp * 64 + lane;
        const int g   = s >> 7;
        const int pr  = s & 127;
        const int row = pr ^ g;
        const bool isA = p < HL;
        const ushort* base;
        ushort* plbase;
        if constexpr (DUAL) {
            base   = (p == 0) ? Ah : (p == 1) ? Al : (p == 2) ? Bh : Bl;
            plbase = (p < 2) ? &As[p][0][0][0] : &Bs[p - 2][0][0][0];
        } else {
            base   = (p == 0) ? Ah : Bh;
            plbase = (p == 0) ? &As[0][0][0][0] : &Bs[0][0][0][0];
        }
        const int mn = isA ? m0 : n0;
        const int ld = isA ? lda : ldb;
        gsrc[q] = base + (size_t)(mn + row) * ld + g * 8;
        ldst[q] = plbase + cp * 512;
    }

    f32x4 acc[4][4] = {};
    const int g4 = lane >> 4, r15 = lane & 15;
    const int wm = wid >> 1, wn = wid & 1;

    #pragma unroll
    for (int q = 0; q < NQ; ++q) gll16(gsrc[q], ldst[q]);

    for (int k0 = 0; k0 < K; k0 += 32) {
        __syncthreads();
        frag_t a_h[4], a_l[4], b_h[4], b_l[4];
        #pragma unroll
        for (int i = 0; i < 4; ++i) {
            const int pr = (wm * 64 + i * 16 + r15) ^ g4;
            a_h[i] = *(const frag_t*)&As[0][g4][pr][0];
            if constexpr (DUAL) a_l[i] = *(const frag_t*)&As[1][g4][pr][0];
        }
        #pragma unroll
        for (int j = 0; j < 4; ++j) {
            const int pr = (wn * 64 + j * 16 + r15) ^ g4;
            b_h[j] = *(const frag_t*)&Bs[0][g4][pr][0];
            if constexpr (DUAL) b_l[j] = *(const frag_t*)&Bs[1][g4][pr][0];
        }
        __syncthreads();
        if (k0 + 32 < K) {
            #pragma unroll
            for (int q = 0; q < NQ; ++q) gll16(gsrc[q] + (k0 + 32), ldst[q]);
        }
        #pragma unroll
        for (int i = 0; i < 4; ++i)
            #pragma unroll
            for (int j = 0; j < 4; ++j) {
                acc[i][j] = mfma16(a_h[i], b_h[j], acc[i][j]);
                if constexpr (DUAL) {
                    acc[i][j] = mfma16(a_h[i], b_l[j], acc[i][j]);
                    acc[i][j] = mfma16(a_l[i], b_h[j], acc[i][j]);
                }
            }
    }

    if constexpr (EMIT == 3) {
        // qkv mode: q cols -> bf16-hi row-major (scores A + flash Q);
        // k cols -> bf16-hi row-major AND packed per-head kh[b*8+h][n][64];
        // v cols -> vt[b*512+c][n] only.
        #pragma unroll
        for (int i = 0; i < 4; ++i) {
            const int row0 = m0 + wm * 64 + i * 16 + g4 * 4;   // 4 consecutive rows
            const int bq = row0 >> 10, n = row0 & 1023;
            #pragma unroll
            for (int j = 0; j < 4; ++j) {
                const int col = n0 + wn * 64 + j * 16 + r15;
                u4u pk;
                #pragma unroll
                for (int r = 0; r < 4; ++r) pk.s[r] = f2bf(acc[i][j][r]);
                if (col < 1024) {
                    #pragma unroll
                    for (int r = 0; r < 4; ++r)
                        Ch[(size_t)(row0 + r) * ldc + col] = pk.s[r];
                }
                if (col >= 1024) {
                    const int c = col - 1024;          // h*64 + d
                    *(ushort4*)(Cv + (((size_t)(bq * 512 + c)) << 10) + n) = pk.v;
                } else if (col >= 512) {
                    const int c = col - 512;           // h*64 + d
                    const size_t base = ((size_t)(bq * 8 + (c >> 6)) * 1024 + n) * 64 + (c & 63);
                    #pragma unroll
                    for (int r = 0; r < 4; ++r) Ck[base + (size_t)r * 64] = pk.s[r];
                }
            }
        }
    } else {
        if constexpr (EMIT == 0) Cf += (size_t)z * sC;
        #pragma unroll
        for (int i = 0; i < 4; ++i)
            #pragma unroll
            for (int r = 0; r < 4; ++r) {
                const int row = m0 + wm * 64 + i * 16 + g4 * 4 + r;
                #pragma unroll
                for (int j = 0; j < 4; ++j) {
                    const int col = n0 + wn * 64 + j * 16 + r15;
                    float vv = acc[i][j][r] * scale;
                    if constexpr (BIAS) vv += bias[col];
                    if constexpr (RES)  vv += res[(size_t)row * ldc + col];
                    if constexpr (GELU) vv = 0.5f * vv * (1.f + erff(vv * 0.70710678118654752f));
                    const size_t o = (size_t)row * ldc + col;
                    if constexpr (EMIT == 0) Cf[o] = vv;
                    if constexpr (EMIT == 2) {
                        const ushort hi = f2bf(vv);
                        Ch[o] = hi;
                        Cl[o] = f2bf(vv - bf2f(hi));
                    }
                }
            }
    }
}

// ---------- fused full-dim scores + row softmax ----------
// One block = 32 q-rows x 1024 key-cols of one batch. grid 256 (b = bid&7 -> XCD pin,
// 1 MB K-matrix L2-resident per XCD; 1 block/CU). A = q rows (qkv_h), B = packed kh.
// Row max/sum via shfl_xor(16) + LDS cross-wave reduce; writes final attn f32 once.
__global__ __launch_bounds__(256, 1) void k_scoresm(const ushort* __restrict__ qh,
                                                    const ushort* __restrict__ kh,
                                                    float* __restrict__ attn) {
    const int bid = blockIdx.x;
    const int b = bid & 7, strip = bid >> 3;       // strip 0..31
    const int tid = threadIdx.x, lane = tid & 63, wid = tid >> 6;
    const int g4 = lane >> 4, r15 = lane & 15;
    const int w256 = wid * 256;
    const int m0 = b * NN_ + strip * 32;           // global q-row base
    __shared__ float redA[4][32];
    __shared__ float redB[4][32];

    f32x4 acc[2][16] = {};
    const ushort* khb = kh + ((size_t)(b * 8) << 16);
    for (int ks = 0; ks < 16; ks++) {
        frag_t a[2];
        #pragma unroll
        for (int m = 0; m < 2; m++)
            a[m] = *(const frag_t*)(qh + (size_t)(m0 + m * 16 + r15) * 1536 + ks * 32 + g4 * 8);
        const ushort* bp = khb + ((size_t)(ks >> 1) << 16) + ((ks & 1) << 5) + g4 * 8;
        #pragma unroll
        for (int j = 0; j < 16; j++) {
            const frag_t bf = *(const frag_t*)(bp + (size_t)(w256 + j * 16 + r15) * 64);
            acc[0][j] = mfma16(a[0], bf, acc[0][j]);
            acc[1][j] = mfma16(a[1], bf, acc[1][j]);
        }
    }
    // scale
    const float scale = 0.044194173824159216f;     // 512^-0.5
    #pragma unroll
    for (int m = 0; m < 2; m++)
        #pragma unroll
        for (int j = 0; j < 16; j++) acc[m][j] = acc[m][j] * scale;
    // row max (lane-local over j, shfl over 16 lanes, LDS over 4 waves)
    float rowM[2][4];
    #pragma unroll
    for (int m = 0; m < 2; m++)
        #pragma unroll
        for (int r = 0; r < 4; r++) {
            float mx = acc[m][0][r];
            #pragma unroll
            for (int j = 1; j < 16; j++) mx = fmaxf(mx, acc[m][j][r]);
            #pragma unroll
            for (int off = 1; off < 16; off <<= 1) mx = fmaxf(mx, __shfl_xor(mx, off, 16));
            if (r15 == 0) redA[wid][m * 16 + g4 * 4 + r] = mx;
        }
    __syncthreads();
    #pragma unroll
    for (int m = 0; m < 2; m++)
        #pragma unroll
        for (int r = 0; r < 4; r++) {
            const int row = m * 16 + g4 * 4 + r;
            rowM[m][r] = fmaxf(fmaxf(redA[0][row], redA[1][row]),
                               fmaxf(redA[2][row], redA[3][row]));
        }
    // exp + row sum
    float rowS[2][4];
    #pragma unroll
    for (int m = 0; m < 2; m++)
        #pragma unroll
        for (int r = 0; r < 4; r++) {
            float s = 0.f;
            #pragma unroll
            for (int j = 0; j < 16; j++) {
                const float e = __expf(acc[m][j][r] - rowM[m][r]);
                acc[m][j][r] = e;
                s += e;
            }
            #pragma unroll
            for (int off = 1; off < 16; off <<= 1) s += __shfl_xor(s, off, 16);
            if (r15 == 0) redB[wid][m * 16 + g4 * 4 + r] = s;
        }
    __syncthreads();
    #pragma unroll
    for (int m = 0; m < 2; m++)
        #pragma unroll
        for (int r = 0; r < 4; r++) {
            const int row = m * 16 + g4 * 4 + r;
            rowS[m][r] = 1.f / (redB[0][row] + redB[1][row] + redB[2][row] + redB[3][row]);
        }
    // write final attn (f32)
    float* ab = attn + ((size_t)b << 20) + (size_t)(strip * 32) * 1024;
    #pragma unroll
    for (int m = 0; m < 2; m++)
        #pragma unroll
        for (int r = 0; r < 4; r++) {
            float* rp = ab + (size_t)(m * 16 + g4 * 4 + r) * 1024 + w256 + r15;
            #pragma unroll
            for (int j = 0; j < 16; j++) rp[j * 16] = acc[m][j][r] * rowS[m][r];
        }
}

// ---------- per-head flash attention, MFMA bf16, latency-pipelined ----------
// grid 512: XCD pin (bid&7); 32 q-rows per wave (2 m-frags), 128 per block.
// K-frags for kt+1 reloaded in place right after current S-MFMAs consume them
// (issued before the bounce fences -> softmax+bounce hides load latency).
__global__ __launch_bounds__(256) void k_flash(const ushort* __restrict__ qkv,
                                               const ushort* __restrict__ kh,
                                               const ushort* __restrict__ vt,
                                               ushort* __restrict__ oh,
                                               ushort* __restrict__ ol) {
    const int bid = blockIdx.x;
    const int xcd = bid & 7, jj = bid >> 3;
    const int qt  = jj & 7;
    const int pid = xcd + 8 * (jj >> 3);       // 0..63
    const int b = pid >> 3, h = pid & 7;
    const int tid = threadIdx.x, lane = tid & 63, wid = tid >> 6;
    const int g4 = lane >> 4, r15 = lane & 15;
    __shared__ ushort Pt[4][64][44];           // [wave][k][q(32)+pad], stride 44: write-conflict-free
    ushort (*pw)[44] = Pt[wid];

    const int q0 = qt * 128 + wid * 32;
    frag_t qa[2][2];
    #pragma unroll
    for (int m = 0; m < 2; m++) {
        const ushort* qp = qkv + (size_t)(b * NN_ + q0 + m * 16 + r15) * 1536 + h * 64 + g4 * 8;
        qa[m][0] = *(const frag_t*)qp;
        qa[m][1] = *(const frag_t*)(qp + 32);
    }
    const ushort* kbase = kh + ((size_t)(b * 8 + h) << 16) + g4 * 8;   // [n][64]
    const ushort* vbase = vt + ((size_t)(b * 8 + h) * 64) * 1024 + g4 * 8;

    float mR[2][4], lR[2][4];
    f32x4 O[2][4];
    #pragma unroll
    for (int m = 0; m < 2; m++)
        #pragma unroll
        for (int r = 0; r < 4; r++) { mR[m][r] = -INFINITY; lR[m][r] = 0.f; }
    #pragma unroll
    for (int m = 0; m < 2; m++)
        #pragma unroll
        for (int j = 0; j < 4; j++) O[m][j] = (f32x4){0.f, 0.f, 0.f, 0.f};

    // preload K-frags for kt=0
    frag_t kf[4][2];
    #pragma unroll
    for (int j = 0; j < 4; j++) {
        const ushort* kp = kbase + (size_t)(j * 16 + r15) * 64;
        kf[j][0] = *(const frag_t*)kp;
        kf[j][1] = *(const frag_t*)(kp + 32);
    }

    for (int kt = 0; kt < 16; kt++) {
        // V fragments for current tile (used after softmax+bounce -> latency covered)
        frag_t vf[4][2];
        #pragma unroll
        for (int j = 0; j < 4; j++) {
            const ushort* vp = vbase + (size_t)(j * 16 + r15) * 1024 + kt * 64;
            vf[j][0] = *(const frag_t*)vp;
            vf[j][1] = *(const frag_t*)(vp + 32);
        }
        // S = Q @ K^T
        f32x4 S[2][4];
        #pragma unroll
        for (int m = 0; m < 2; m++)
            #pragma unroll
            for (int j = 0; j < 4; j++) {
                f32x4 s = {0.f, 0.f, 0.f, 0.f};
                s = mfma16(qa[m][0], kf[j][0], s);
                s = mfma16(qa[m][1], kf[j][1], s);
                S[m][j] = s * 0.125f;
            }
        // prefetch next tile's K in place (latency hidden under softmax + bounce)
        if (kt < 15) {
            #pragma unroll
            for (int j = 0; j < 4; j++) {
                const ushort* kp = kbase + (size_t)((kt + 1) * 64 + j * 16 + r15) * 64;
                kf[j][0] = *(const frag_t*)kp;
                kf[j][1] = *(const frag_t*)(kp + 32);
            }
        }
        // online softmax per row
        #pragma unroll
        for (int m = 0; m < 2; m++) {
            float alpha[4];
            #pragma unroll
            for (int r = 0; r < 4; r++) {
                float mx = fmaxf(fmaxf(S[m][0][r], S[m][1][r]), fmaxf(S[m][2][r], S[m][3][r]));
                #pragma unroll
                for (int off = 1; off < 16; off <<= 1) mx = fmaxf(mx, __shfl_xor(mx, off, 16));
                const float mn = fmaxf(mR[m][r], mx);
                alpha[r] = __expf(mR[m][r] - mn);
                mR[m][r] = mn;
            }
            #pragma unroll
            for (int j = 0; j < 4; j++)
                #pragma unroll
                for (int r = 0; r < 4; r++) S[m][j][r] = __expf(S[m][j][r] - mR[m][r]);
            #pragma unroll
            for (int r = 0; r < 4; r++) {
                float s = S[m][0][r] + S[m][1][r] + S[m][2][r] + S[m][3][r];
                #pragma unroll
                for (int off = 1; off < 16; off <<= 1) s += __shfl_xor(s, off, 16);
                lR[m][r] = lR[m][r] * alpha[r] + s;
            }
            #pragma unroll
            for (int j = 0; j < 4; j++) {
                f32x4 o = O[m][j];
                #pragma unroll
                for (int r = 0; r < 4; r++) o[r] *= alpha[r];
                O[m][j] = o;
            }
        }
        // P -> LDS transpose bounce: Pt[k = 16j + r15][q = m*16 + 4*g4 + r]
        asm volatile("s_waitcnt lgkmcnt(0)" ::: "memory");
        #pragma unroll
        for (int m = 0; m < 2; m++)
            #pragma unroll
            for (int j = 0; j < 4; j++) {
                u4u pk;
                #pragma unroll
                for (int r = 0; r < 4; r++) pk.s[r] = f2bf(S[m][j][r]);
                *(ushort4*)&pw[j * 16 + r15][m * 16 + g4 * 4] = pk.v;
            }
        asm volatile("s_waitcnt lgkmcnt(0)" ::: "memory");
        // P as A-operand: lane holds P[q = m*16 + r15][k = x*32 + g4*8 + e]
        frag_t pa[2][2];
        #pragma unroll
        for (int m = 0; m < 2; m++) {
            u8u t0, t1;
            #pragma unroll
            for (int e = 0; e < 8; e++) {
                t0.u[e] = pw[g4 * 8 + e][m * 16 + r15];
                t1.u[e] = pw[32 + g4 * 8 + e][m * 16 + r15];
            }
            pa[m][0] = t0.f; pa[m][1] = t1.f;
        }
        #pragma unroll
        for (int m = 0; m < 2; m++)
            #pragma unroll
            for (int j = 0; j < 4; j++) {
                O[m][j] = mfma16(pa[m][0], vf[j][0], O[m][j]);
                O[m][j] = mfma16(pa[m][1], vf[j][1], O[m][j]);
            }
    }
    // epilogue: normalize, emit bf16 hi/lo
    #pragma unroll
    for (int m = 0; m < 2; m++)
        #pragma unroll
        for (int r = 0; r < 4; r++) {
            const float inv = 1.f / lR[m][r];
            const size_t rbase = (size_t)(b * NN_ + q0 + m * 16 + 4 * g4 + r) * 512 + h * 64;
            #pragma unroll
            for (int j = 0; j < 4; j++) {
                const float y = O[m][j][r] * inv;
                const ushort hi = f2bf(y);
                oh[rbase + j * 16 + r15] = hi;
                ol[rbase + j * 16 + r15] = f2bf(y - bf2f(hi));
            }
        }
}

extern "C" void kernel_launch(void* const* d_in, const int* in_sizes, int n_in,
                              void* d_out, int out_size, void* d_ws, size_t ws_size,
                              hipStream_t stream) {
    (void)in_sizes; (void)n_in; (void)out_size; (void)ws_size;
    const float* x_in  = (const float*)d_in[0];
    const float* ln1_g = (const float*)d_in[1];
    const float* ln1_b = (const float*)d_in[2];
    const float* w_qkv = (const float*)d_in[3];
    const float* w_o   = (const float*)d_in[4];
    const float* b_o   = (const float*)d_in[5];
    const float* ln2_g = (const float*)d_in[6];
    const float* ln2_b = (const float*)d_in[7];
    const float* w1    = (const float*)d_in[8];
    const float* b1    = (const float*)d_in[9];
    const float* w2    = (const float*)d_in[10];
    const float* b2    = (const float*)d_in[11];
    float* out_x    = (float*)d_out;            // [8192, 512]
    float* out_attn = (float*)d_out + XSZ_;     // [6, 8, 1024, 1024]

    // workspace: xf | h hi/lo | qkv_h | vt | kh | ff_l | W^T  (ff_h aliases qkv_h+vt exactly)
    float*  xf    = (float*)d_ws;               // 16.8 MB
    ushort* h_hi  = (ushort*)(xf + XSZ_);       //  8.4 MB
    ushort* h_lo  = h_hi + XSZ_;                //  8.4 MB
    ushort* qkv_h = h_lo + XSZ_;                // 25.2 MB
    ushort* vtb   = qkv_h + QKVSZ_;             //  8.4 MB
    ushort* khb   = vtb + VTSZ_;                //  8.4 MB
    ushort* ff_h  = qkv_h;                      // aliases qkv_h+vt exactly (FFSZ_ elements)
    ushort* ff_l  = khb + VTSZ_;                // 33.6 MB
    ushort* wq_h  = ff_l + FFSZ_;               // W^T planes, 75.5 MB total
    ushort* wq_l  = wq_h + (size_t)6 * 786432;
    ushort* wo_h  = wq_l + (size_t)6 * 786432;
    ushort* wo_l  = wo_h + (size_t)6 * 262144;
    ushort* w1_h  = wo_l + (size_t)6 * 262144;
    ushort* w1_l  = w1_h + (size_t)6 * 1048576;
    ushort* w2_h  = w1_l + (size_t)6 * 1048576;
    ushort* w2_l  = w2_h + (size_t)6 * 1048576;

    k_wsplit<<<dim3(24, 8, 6), 256, 0, stream>>>(w_qkv, wq_h, wq_l, 512, 1536);
    k_wsplit<<<dim3( 8, 8, 6), 256, 0, stream>>>(w_o,   wo_h, wo_l, 512, 512);
    k_wsplit<<<dim3(32, 8, 6), 256, 0, stream>>>(w1,    w1_h, w1_l, 512, 2048);
    k_wsplit<<<dim3( 8,32, 6), 256, 0, stream>>>(w2,    w2_h, w2_l, 2048, 512);
    hipMemcpyAsync(xf, x_in, (size_t)XSZ_ * sizeof(float), hipMemcpyDeviceToDevice, stream);

    for (int l = 0; l < L_; l++) {
        float* attn_l = out_attn + (size_t)l * ATTN_LAYER_SZ_;
        // PreNorm attention
        k_ln<<<2048, 256, 0, stream>>>(xf, ln1_g + l * 512, ln1_b + l * 512, h_hi, h_lo);
        // qkv = h @ w_qkv : dual 3-pass; emits bf16-hi (q,k) + packed K + transposed V
        k_mm<true, 3, false, false, false><<<dim3(12, 64), 256, 0, stream>>>(
            h_hi, h_lo, 512, 0, wq_h + (size_t)l * 786432, wq_l + (size_t)l * 786432, 512, 0,
            nullptr, nullptr, nullptr, qkv_h, nullptr, khb, vtb, 1536, 0, 512, 1.f);
        // fused full-dim scores + softmax -> attn (f32, written once)
        k_scoresm<<<256, 256, 0, stream>>>(qkv_h, khb, attn_l);
        // per-head flash attention (MFMA bf16, pipelined, XCD-pinned) -> o in h hi/lo
        k_flash<<<512, 256, 0, stream>>>(qkv_h, khb, vtb, h_hi, h_lo);
        // x += o @ w_o + b_o
        k_mm<true, 0, true, true, false><<<dim3(4, 64), 256, 0, stream>>>(
            h_hi, h_lo, 512, 0, wo_h + (size_t)l * 262144, wo_l + (size_t)l * 262144, 512, 0,
            b_o + l * 512, xf, xf, nullptr, nullptr, nullptr, nullptr, 512, 0, 512, 1.f);
        // PreNorm FFN
        k_ln<<<2048, 256, 0, stream>>>(xf, ln2_g + l * 512, ln2_b + l * 512, h_hi, h_lo);
        k_mm<true, 2, true, false, true><<<dim3(16, 64), 256, 0, stream>>>(
            h_hi, h_lo, 512, 0, w1_h + (size_t)l * 1048576, w1_l + (size_t)l * 1048576, 512, 0,
            b1 + l * 2048, nullptr, nullptr, ff_h, ff_l, nullptr, nullptr, 2048, 0, 512, 1.f);
        k_mm<true, 0, true, true, false><<<dim3(4, 64), 256, 0, stream>>>(
            ff_h, ff_l, 2048, 0, w2_h + (size_t)l * 1048576, w2_l + (size_t)l * 1048576, 2048, 0,
            b2 + l * 512, xf, (l == L_ - 1) ? out_x : xf, nullptr, nullptr, nullptr, nullptr,
            512, 0, 2048, 1.f);
    }
}

// Round 7
// 1927.282 us; speedup vs baseline: 1.5573x; 1.4144x over previous
//
#include <hip/hip_runtime.h>
#include <stdint.h>
#include <type_traits>
#include <utility>

// Problem constants
#define L_   6
#define D_   512
#define MLP_ 2048
#define BB_  8
#define NN_  1024
#define ROWS_ 8192              // BB_*NN_
#define XSZ_  4194304           // ROWS_*D_   (output 0 size)
#define VTSZ_  4194304          // BB_*512*NN_ (elements)
#define FFSZ_  16777216         // ROWS_*2048 (elements)
#define ATTN_LAYER_SZ_ 8388608  // BB_*NN_*NN_ (per-layer attn slice)

typedef union { float4 v; float f[4]; } f4u;
typedef union { ushort4 v; ushort s[4]; } u4u;

typedef __attribute__((ext_vector_type(8))) short    s16x8;
typedef __attribute__((ext_vector_type(8))) _Float16 h16x8;
typedef __attribute__((ext_vector_type(4))) float    f32x4;

// Toolchain-portable fragment type for the gfx950 f16 MFMA builtin.
template<class V, class = void> struct mfma_f16_short : std::false_type {};
template<class V> struct mfma_f16_short<V, std::void_t<decltype(
    __builtin_amdgcn_mfma_f32_16x16x32_f16(std::declval<V>(), std::declval<V>(),
                                           std::declval<f32x4>(), 0, 0, 0))>>
    : std::true_type {};
using frag_t = std::conditional_t<mfma_f16_short<s16x8>::value, s16x8, h16x8>;

typedef union { frag_t f; ushort u[8]; } u8u;

__device__ __forceinline__ f32x4 mfma16(frag_t a, frag_t b, f32x4 c) {
  return __builtin_amdgcn_mfma_f32_16x16x32_f16(a, b, c, 0, 0, 0);
}

// f32 -> f16 (RNE, hardware cvt)
__device__ __forceinline__ ushort f2h(float x) {
  return __builtin_bit_cast(unsigned short, (_Float16)x);
}

// async global->LDS, 16B per lane, wave-linear LDS destination
__device__ __forceinline__ void gll16(const void* g, void* l) {
  __builtin_amdgcn_global_load_lds((__attribute__((address_space(1))) void*)g,
                                   (__attribute__((address_space(3))) void*)l,
                                   16, 0, 0);
}

// ---------- LayerNorm: one wave per row (D=512 -> 8 elems/lane), emits f16 ----------
__global__ __launch_bounds__(256) void k_ln(const float* __restrict__ x,
                                            const float* __restrict__ g,
                                            const float* __restrict__ bia,
                                            ushort* __restrict__ hh) {
    const int row  = blockIdx.x * 4 + (threadIdx.x >> 6);
    const int lane = threadIdx.x & 63;
    const float* xr = x + (size_t)row * D_;
    float v[8]; float s = 0.f, sq = 0.f;
    #pragma unroll
    for (int j = 0; j < 8; j++) { v[j] = xr[lane + j * 64]; s += v[j]; sq += v[j] * v[j]; }
    #pragma unroll
    for (int off = 32; off >= 1; off >>= 1) {
        s  += __shfl_xor(s, off, 64);
        sq += __shfl_xor(sq, off, 64);
    }
    const float mean = s * (1.f / D_);
    const float var  = sq * (1.f / D_) - mean * mean;
    const float rstd = rsqrtf(var + 1e-5f);
    ushort* hr = hh + (size_t)row * D_;
    #pragma unroll
    for (int j = 0; j < 8; j++) {
        int col = lane + j * 64;
        hr[col] = f2h((v[j] - mean) * rstd * g[col] + bia[col]);
    }
}

// ---------- one-time weight transpose + f16 cast: W[l][K][N] -> T[l][N][K] ----------
__global__ __launch_bounds__(256) void k_wsplit(const float* __restrict__ W,
                                                ushort* __restrict__ Th,
                                                int K, int N) {
    __shared__ float t[64][65];
    const int n0 = blockIdx.x * 64, k0 = blockIdx.y * 64;
    const size_t lay = (size_t)blockIdx.z * K * N;
    const int tid = threadIdx.x;
    const int r = tid >> 4, c4 = (tid & 15) * 4;
    #pragma unroll
    for (int p = 0; p < 4; p++) {
        const float4 v = *(const float4*)(W + lay + (size_t)(k0 + r + p * 16) * N + n0 + c4);
        t[r + p * 16][c4 + 0] = v.x; t[r + p * 16][c4 + 1] = v.y;
        t[r + p * 16][c4 + 2] = v.z; t[r + p * 16][c4 + 3] = v.w;
    }
    __syncthreads();
    #pragma unroll
    for (int p = 0; p < 4; p++) {
        const int n = r + p * 16;
        u4u hv;
        #pragma unroll
        for (int j = 0; j < 4; j++) hv.s[j] = f2h(t[c4 + j][n]);
        *(ushort4*)(Th + lay + (size_t)(n0 + n) * K + k0 + c4) = hv.v;
    }
}

// ---------- MFMA GEMM: C[M,N] = A[M,K] @ B^T[N,K]^T, f16 inputs, f32 accumulate ----------
// 128x128 tile, BK=32, 4 waves, 4x4 frags, global_load_lds staging with XOR row-swizzle.
// EMIT: 0 = f32 (Cf, +BIAS/+RES); 2 = f16 (Ch, +BIAS/+GELU);
//       3 = qkv mode: q cols -> qh[8192][512], k cols -> packed kh, v cols -> transposed vt.
template<int EMIT, bool BIAS, bool RES, bool GELU>
__global__ __launch_bounds__(256, 2) void k_mm(
        const ushort* __restrict__ A, int lda,
        const ushort* __restrict__ B, int ldb,
        const float* __restrict__ bias, const float* __restrict__ res,
        float* __restrict__ Cf, ushort* __restrict__ Ch,
        ushort* __restrict__ Ck, ushort* __restrict__ Cv,
        int ldc, int K)
{
    __shared__ __align__(16) ushort As[4][128][8];
    __shared__ __align__(16) ushort Bs[4][128][8];
    const int tid = threadIdx.x, lane = tid & 63, wid = tid >> 6;
    const int m0 = blockIdx.y * 128, n0 = blockIdx.x * 128;

    const ushort* gsrc[4];
    ushort*       ldst[4];
    #pragma unroll
    for (int q = 0; q < 4; ++q) {
        const int cid = q * 4 + wid;
        const int p   = cid >> 3;          // 0 = A, 1 = B
        const int cp  = cid & 7;
        const int s   = cp * 64 + lane;
        const int g   = s >> 7;
        const int pr  = s & 127;
        const int row = pr ^ g;            // XOR swizzle on the GLOBAL source
        const ushort* base = (p == 0) ? A : B;
        ushort* plbase     = (p == 0) ? &As[0][0][0] : &Bs[0][0][0];
        const int mn = (p == 0) ? m0 : n0;
        const int ld = (p == 0) ? lda : ldb;
        gsrc[q] = base + (size_t)(mn + row) * ld + g * 8;
        ldst[q] = plbase + cp * 512;
    }

    f32x4 acc[4][4] = {};
    const int g4 = lane >> 4, r15 = lane & 15;
    const int wm = wid >> 1, wn = wid & 1;

    #pragma unroll
    for (int q = 0; q < 4; ++q) gll16(gsrc[q], ldst[q]);

    for (int k0 = 0; k0 < K; k0 += 32) {
        __syncthreads();
        frag_t a[4], b[4];
        #pragma unroll
        for (int i = 0; i < 4; ++i)
            a[i] = *(const frag_t*)&As[g4][(wm * 64 + i * 16 + r15) ^ g4][0];
        #pragma unroll
        for (int j = 0; j < 4; ++j)
            b[j] = *(const frag_t*)&Bs[g4][(wn * 64 + j * 16 + r15) ^ g4][0];
        __syncthreads();
        if (k0 + 32 < K) {
            #pragma unroll
            for (int q = 0; q < 4; ++q) gll16(gsrc[q] + (k0 + 32), ldst[q]);
        }
        #pragma unroll
        for (int i = 0; i < 4; ++i)
            #pragma unroll
            for (int j = 0; j < 4; ++j)
                acc[i][j] = mfma16(a[i], b[j], acc[i][j]);
    }

    if constexpr (EMIT == 3) {
        // q cols -> qh[8192][512]; k cols -> kh[b*8+h][n][64]; v cols -> vt[b*512+c][n]
        #pragma unroll
        for (int i = 0; i < 4; ++i) {
            const int row0 = m0 + wm * 64 + i * 16 + g4 * 4;   // 4 consecutive rows
            const int bq = row0 >> 10, n = row0 & 1023;
            #pragma unroll
            for (int j = 0; j < 4; ++j) {
                const int col = n0 + wn * 64 + j * 16 + r15;
                u4u pk;
                #pragma unroll
                for (int r = 0; r < 4; ++r) pk.s[r] = f2h(acc[i][j][r]);
                if (col < 512) {
                    #pragma unroll
                    for (int r = 0; r < 4; ++r)
                        Ch[(size_t)(row0 + r) * 512 + col] = pk.s[r];
                } else if (col < 1024) {
                    const int c = col - 512;           // h*64 + d
                    const size_t base = ((size_t)(bq * 8 + (c >> 6)) * 1024 + n) * 64 + (c & 63);
                    #pragma unroll
                    for (int r = 0; r < 4; ++r) Ck[base + (size_t)r * 64] = pk.s[r];
                } else {
                    const int c = col - 1024;          // h*64 + d
                    *(ushort4*)(Cv + (((size_t)(bq * 512 + c)) << 10) + n) = pk.v;
                }
            }
        }
    } else {
        #pragma unroll
        for (int i = 0; i < 4; ++i)
            #pragma unroll
            for (int r = 0; r < 4; ++r) {
                const int row = m0 + wm * 64 + i * 16 + g4 * 4 + r;
                #pragma unroll
                for (int j = 0; j < 4; ++j) {
                    const int col = n0 + wn * 64 + j * 16 + r15;
                    float vv = acc[i][j][r];
                    if constexpr (BIAS) vv += bias[col];
                    if constexpr (RES)  vv += res[(size_t)row * ldc + col];
                    if constexpr (GELU) vv = 0.5f * vv * (1.f + erff(vv * 0.70710678118654752f));
                    const size_t o = (size_t)row * ldc + col;
                    if constexpr (EMIT == 0) Cf[o] = vv;
                    if constexpr (EMIT == 2) Ch[o] = f2h(vv);
                }
            }
    }
}

// ---------- fused full-dim scores + row softmax ----------
// One block = 32 q-rows x 1024 key-cols of one batch. grid 256 (b = bid&7 -> XCD pin,
// 1 MB K-matrix L2-resident per XCD; 1 block/CU). A = q rows (qh), B = packed kh.
__global__ __launch_bounds__(256, 1) void k_scoresm(const ushort* __restrict__ qh,
                                                    const ushort* __restrict__ kh,
                                                    float* __restrict__ attn) {
    const int bid = blockIdx.x;
    const int b = bid & 7, strip = bid >> 3;       // strip 0..31
    const int tid = threadIdx.x, lane = tid & 63, wid = tid >> 6;
    const int g4 = lane >> 4, r15 = lane & 15;
    const int w256 = wid * 256;
    const int m0 = b * NN_ + strip * 32;           // global q-row base
    __shared__ float redA[4][32];
    __shared__ float redB[4][32];

    f32x4 acc[2][16] = {};
    const ushort* khb = kh + ((size_t)(b * 8) << 16);
    for (int ks = 0; ks < 16; ks++) {
        frag_t a[2];
        #pragma unroll
        for (int m = 0; m < 2; m++)
            a[m] = *(const frag_t*)(qh + (size_t)(m0 + m * 16 + r15) * 512 + ks * 32 + g4 * 8);
        const ushort* bp = khb + ((size_t)(ks >> 1) << 16) + ((ks & 1) << 5) + g4 * 8;
        #pragma unroll
        for (int j = 0; j < 16; j++) {
            const frag_t bf = *(const frag_t*)(bp + (size_t)(w256 + j * 16 + r15) * 64);
            acc[0][j] = mfma16(a[0], bf, acc[0][j]);
            acc[1][j] = mfma16(a[1], bf, acc[1][j]);
        }
    }
    const float scale = 0.044194173824159216f;     // 512^-0.5
    #pragma unroll
    for (int m = 0; m < 2; m++)
        #pragma unroll
        for (int j = 0; j < 16; j++) acc[m][j] = acc[m][j] * scale;
    float rowM[2][4];
    #pragma unroll
    for (int m = 0; m < 2; m++)
        #pragma unroll
        for (int r = 0; r < 4; r++) {
            float mx = acc[m][0][r];
            #pragma unroll
            for (int j = 1; j < 16; j++) mx = fmaxf(mx, acc[m][j][r]);
            #pragma unroll
            for (int off = 1; off < 16; off <<= 1) mx = fmaxf(mx, __shfl_xor(mx, off, 16));
            if (r15 == 0) redA[wid][m * 16 + g4 * 4 + r] = mx;
        }
    __syncthreads();
    #pragma unroll
    for (int m = 0; m < 2; m++)
        #pragma unroll
        for (int r = 0; r < 4; r++) {
            const int row = m * 16 + g4 * 4 + r;
            rowM[m][r] = fmaxf(fmaxf(redA[0][row], redA[1][row]),
                               fmaxf(redA[2][row], redA[3][row]));
        }
    float rowS[2][4];
    #pragma unroll
    for (int m = 0; m < 2; m++)
        #pragma unroll
        for (int r = 0; r < 4; r++) {
            float s = 0.f;
            #pragma unroll
            for (int j = 0; j < 16; j++) {
                const float e = __expf(acc[m][j][r] - rowM[m][r]);
                acc[m][j][r] = e;
                s += e;
            }
            #pragma unroll
            for (int off = 1; off < 16; off <<= 1) s += __shfl_xor(s, off, 16);
            if (r15 == 0) redB[wid][m * 16 + g4 * 4 + r] = s;
        }
    __syncthreads();
    #pragma unroll
    for (int m = 0; m < 2; m++)
        #pragma unroll
        for (int r = 0; r < 4; r++) {
            const int row = m * 16 + g4 * 4 + r;
            rowS[m][r] = 1.f / (redB[0][row] + redB[1][row] + redB[2][row] + redB[3][row]);
        }
    float* ab = attn + ((size_t)b << 20) + (size_t)(strip * 32) * 1024;
    #pragma unroll
    for (int m = 0; m < 2; m++)
        #pragma unroll
        for (int r = 0; r < 4; r++) {
            float* rp = ab + (size_t)(m * 16 + g4 * 4 + r) * 1024 + w256 + r15;
            #pragma unroll
            for (int j = 0; j < 16; j++) rp[j * 16] = acc[m][j][r] * rowS[m][r];
        }
}

// ---------- per-head flash attention, MFMA f16, latency-pipelined ----------
// grid 512: XCD pin (bid&7); 32 q-rows per wave (2 m-frags), 128 per block.
// K-frags for kt+1 reloaded in place right after current S-MFMAs consume them.
__global__ __launch_bounds__(256) void k_flash(const ushort* __restrict__ qh,
                                               const ushort* __restrict__ kh,
                                               const ushort* __restrict__ vt,
                                               ushort* __restrict__ oh) {
    const int bid = blockIdx.x;
    const int xcd = bid & 7, jj = bid >> 3;
    const int qt  = jj & 7;
    const int pid = xcd + 8 * (jj >> 3);       // 0..63
    const int b = pid >> 3, h = pid & 7;
    const int tid = threadIdx.x, lane = tid & 63, wid = tid >> 6;
    const int g4 = lane >> 4, r15 = lane & 15;
    __shared__ ushort Pt[4][64][44];           // [wave][k][q(32)+pad]
    ushort (*pw)[44] = Pt[wid];

    const int q0 = qt * 128 + wid * 32;
    frag_t qa[2][2];
    #pragma unroll
    for (int m = 0; m < 2; m++) {
        const ushort* qp = qh + (size_t)(b * NN_ + q0 + m * 16 + r15) * 512 + h * 64 + g4 * 8;
        qa[m][0] = *(const frag_t*)qp;
        qa[m][1] = *(const frag_t*)(qp + 32);
    }
    const ushort* kbase = kh + ((size_t)(b * 8 + h) << 16) + g4 * 8;   // [n][64]
    const ushort* vbase = vt + ((size_t)(b * 8 + h) * 64) * 1024 + g4 * 8;

    float mR[2][4], lR[2][4];
    f32x4 O[2][4];
    #pragma unroll
    for (int m = 0; m < 2; m++)
        #pragma unroll
        for (int r = 0; r < 4; r++) { mR[m][r] = -INFINITY; lR[m][r] = 0.f; }
    #pragma unroll
    for (int m = 0; m < 2; m++)
        #pragma unroll
        for (int j = 0; j < 4; j++) O[m][j] = (f32x4){0.f, 0.f, 0.f, 0.f};

    frag_t kf[4][2];
    #pragma unroll
    for (int j = 0; j < 4; j++) {
        const ushort* kp = kbase + (size_t)(j * 16 + r15) * 64;
        kf[j][0] = *(const frag_t*)kp;
        kf[j][1] = *(const frag_t*)(kp + 32);
    }

    for (int kt = 0; kt < 16; kt++) {
        frag_t vf[4][2];
        #pragma unroll
        for (int j = 0; j < 4; j++) {
            const ushort* vp = vbase + (size_t)(j * 16 + r15) * 1024 + kt * 64;
            vf[j][0] = *(const frag_t*)vp;
            vf[j][1] = *(const frag_t*)(vp + 32);
        }
        f32x4 S[2][4];
        #pragma unroll
        for (int m = 0; m < 2; m++)
            #pragma unroll
            for (int j = 0; j < 4; j++) {
                f32x4 s = {0.f, 0.f, 0.f, 0.f};
                s = mfma16(qa[m][0], kf[j][0], s);
                s = mfma16(qa[m][1], kf[j][1], s);
                S[m][j] = s * 0.125f;
            }
        if (kt < 15) {
            #pragma unroll
            for (int j = 0; j < 4; j++) {
                const ushort* kp = kbase + (size_t)((kt + 1) * 64 + j * 16 + r15) * 64;
                kf[j][0] = *(const frag_t*)kp;
                kf[j][1] = *(const frag_t*)(kp + 32);
            }
        }
        #pragma unroll
        for (int m = 0; m < 2; m++) {
            float alpha[4];
            #pragma unroll
            for (int r = 0; r < 4; r++) {
                float mx = fmaxf(fmaxf(S[m][0][r], S[m][1][r]), fmaxf(S[m][2][r], S[m][3][r]));
                #pragma unroll
                for (int off = 1; off < 16; off <<= 1) mx = fmaxf(mx, __shfl_xor(mx, off, 16));
                const float mn = fmaxf(mR[m][r], mx);
                alpha[r] = __expf(mR[m][r] - mn);
                mR[m][r] = mn;
            }
            #pragma unroll
            for (int j = 0; j < 4; j++)
                #pragma unroll
                for (int r = 0; r < 4; r++) S[m][j][r] = __expf(S[m][j][r] - mR[m][r]);
            #pragma unroll
            for (int r = 0; r < 4; r++) {
                float s = S[m][0][r] + S[m][1][r] + S[m][2][r] + S[m][3][r];
                #pragma unroll
                for (int off = 1; off < 16; off <<= 1) s += __shfl_xor(s, off, 16);
                lR[m][r] = lR[m][r] * alpha[r] + s;
            }
            #pragma unroll
            for (int j = 0; j < 4; j++) {
                f32x4 o = O[m][j];
                #pragma unroll
                for (int r = 0; r < 4; r++) o[r] *= alpha[r];
                O[m][j] = o;
            }
        }
        asm volatile("s_waitcnt lgkmcnt(0)" ::: "memory");
        #pragma unroll
        for (int m = 0; m < 2; m++)
            #pragma unroll
            for (int j = 0; j < 4; j++) {
                u4u pk;
                #pragma unroll
                for (int r = 0; r < 4; r++) pk.s[r] = f2h(S[m][j][r]);
                *(ushort4*)&pw[j * 16 + r15][m * 16 + g4 * 4] = pk.v;
            }
        asm volatile("s_waitcnt lgkmcnt(0)" ::: "memory");
        frag_t pa[2][2];
        #pragma unroll
        for (int m = 0; m < 2; m++) {
            u8u t0, t1;
            #pragma unroll
            for (int e = 0; e < 8; e++) {
                t0.u[e] = pw[g4 * 8 + e][m * 16 + r15];
                t1.u[e] = pw[32 + g4 * 8 + e][m * 16 + r15];
            }
            pa[m][0] = t0.f; pa[m][1] = t1.f;
        }
        #pragma unroll
        for (int m = 0; m < 2; m++)
            #pragma unroll
            for (int j = 0; j < 4; j++) {
                O[m][j] = mfma16(pa[m][0], vf[j][0], O[m][j]);
                O[m][j] = mfma16(pa[m][1], vf[j][1], O[m][j]);
            }
    }
    // epilogue: normalize, emit f16
    #pragma unroll
    for (int m = 0; m < 2; m++)
        #pragma unroll
        for (int r = 0; r < 4; r++) {
            const float inv = 1.f / lR[m][r];
            const size_t rbase = (size_t)(b * NN_ + q0 + m * 16 + 4 * g4 + r) * 512 + h * 64;
            #pragma unroll
            for (int j = 0; j < 4; j++)
                oh[rbase + j * 16 + r15] = f2h(O[m][j][r] * inv);
        }
}

extern "C" void kernel_launch(void* const* d_in, const int* in_sizes, int n_in,
                              void* d_out, int out_size, void* d_ws, size_t ws_size,
                              hipStream_t stream) {
    (void)in_sizes; (void)n_in; (void)out_size; (void)ws_size;
    const float* x_in  = (const float*)d_in[0];
    const float* ln1_g = (const float*)d_in[1];
    const float* ln1_b = (const float*)d_in[2];
    const float* w_qkv = (const float*)d_in[3];
    const float* w_o   = (const float*)d_in[4];
    const float* b_o   = (const float*)d_in[5];
    const float* ln2_g = (const float*)d_in[6];
    const float* ln2_b = (const float*)d_in[7];
    const float* w1    = (const float*)d_in[8];
    const float* b1    = (const float*)d_in[9];
    const float* w2    = (const float*)d_in[10];
    const float* b2    = (const float*)d_in[11];
    float* out_x    = (float*)d_out;            // [8192, 512]
    float* out_attn = (float*)d_out + XSZ_;     // [6, 8, 1024, 1024]

    // workspace (~122 MB): xf | h | qh | kh | vt | ff | W^T (all f16 except xf)
    float*  xf  = (float*)d_ws;                 // 16.8 MB
    ushort* hb  = (ushort*)(xf + XSZ_);         //  8.4 MB (LN out; flash o reuses)
    ushort* qh  = hb + XSZ_;                    //  8.4 MB
    ushort* khb = qh + XSZ_;                    //  8.4 MB
    ushort* vtb = khb + VTSZ_;                  //  8.4 MB
    ushort* ffb = vtb + VTSZ_;                  // 33.6 MB
    ushort* wq  = ffb + FFSZ_;                  //  9.4 MB
    ushort* wo  = wq + (size_t)6 * 786432;      //  3.1 MB
    ushort* w1t = wo + (size_t)6 * 262144;      // 12.6 MB
    ushort* w2t = w1t + (size_t)6 * 1048576;    // 12.6 MB

    k_wsplit<<<dim3(24, 8, 6), 256, 0, stream>>>(w_qkv, wq,  512, 1536);
    k_wsplit<<<dim3( 8, 8, 6), 256, 0, stream>>>(w_o,   wo,  512, 512);
    k_wsplit<<<dim3(32, 8, 6), 256, 0, stream>>>(w1,    w1t, 512, 2048);
    k_wsplit<<<dim3( 8,32, 6), 256, 0, stream>>>(w2,    w2t, 2048, 512);
    hipMemcpyAsync(xf, x_in, (size_t)XSZ_ * sizeof(float), hipMemcpyDeviceToDevice, stream);

    for (int l = 0; l < L_; l++) {
        float* attn_l = out_attn + (size_t)l * ATTN_LAYER_SZ_;
        // PreNorm attention
        k_ln<<<2048, 256, 0, stream>>>(xf, ln1_g + l * 512, ln1_b + l * 512, hb);
        // qkv = h @ w_qkv : emits q (row-major) + packed K + transposed V, all f16
        k_mm<3, false, false, false><<<dim3(12, 64), 256, 0, stream>>>(
            hb, 512, wq + (size_t)l * 786432, 512,
            nullptr, nullptr, nullptr, qh, khb, vtb, 512, 512);
        // fused full-dim scores + softmax -> attn (f32, written once)
        k_scoresm<<<256, 256, 0, stream>>>(qh, khb, attn_l);
        // per-head flash attention (MFMA f16, pipelined, XCD-pinned) -> o in hb
        k_flash<<<512, 256, 0, stream>>>(qh, khb, vtb, hb);
        // x += o @ w_o + b_o
        k_mm<0, true, true, false><<<dim3(4, 64), 256, 0, stream>>>(
            hb, 512, wo + (size_t)l * 262144, 512,
            b_o + l * 512, xf, xf, nullptr, nullptr, nullptr, 512, 512);
        // PreNorm FFN
        k_ln<<<2048, 256, 0, stream>>>(xf, ln2_g + l * 512, ln2_b + l * 512, hb);
        k_mm<2, true, false, true><<<dim3(16, 64), 256, 0, stream>>>(
            hb, 512, w1t + (size_t)l * 1048576, 512,
            b1 + l * 2048, nullptr, nullptr, ffb, nullptr, nullptr, 2048, 512);
        k_mm<0, true, true, false><<<dim3(4, 64), 256, 0, stream>>>(
            ffb, 2048, w2t + (size_t)l * 1048576, 2048,
            b2 + l * 512, xf, (l == L_ - 1) ? out_x : xf, nullptr, nullptr, nullptr, 512, 2048);
    }
}